// Round 1
// baseline (2200.987 us; speedup 1.0000x reference)
//
#include <hip/hip_runtime.h>

#define NG 128
#define NN 1024
#define KK 16
#define SLOPE 0.01f

__device__ __forceinline__ float leaky(float v) {
    return v >= 0.0f ? v : SLOPE * v;
}

// ---------------- Layer 1: fused kNN (on xyz) + EdgeConv [6->16->16], sum over k ----
__global__ __launch_bounds__(256) void knn_conv1(
    const float* __restrict__ x,    // [NG*NN*3]
    const float* __restrict__ W1,   // [6*16]
    const float* __restrict__ b1,   // [16]
    const float* __restrict__ W2,   // [16*16]
    const float* __restrict__ b2,   // [16]
    float* __restrict__ h1)         // [NG*NN*16]
{
    __shared__ float4 posq[NN];     // x,y,z,|p|^2
    __shared__ float w1[6 * 16];
    __shared__ float w2[16 * 16];
    __shared__ float bb1[16], bb2[16];

    const int g = blockIdx.x >> 2;
    const int chunk = blockIdx.x & 3;
    const int tid = threadIdx.x;

    if (tid < 96) w1[tid] = W1[tid];
    w2[tid] = W2[tid];
    if (tid < 16) { bb1[tid] = b1[tid]; bb2[tid] = b2[tid]; }

    for (int n = tid; n < NN; n += 256) {
        const float* xp = x + (size_t)(g * NN + n) * 3;
        float px = xp[0], py = xp[1], pz = xp[2];
        posq[n] = make_float4(px, py, pz, px * px + py * py + pz * pz);
    }
    __syncthreads();

    const int i = chunk * 256 + tid;
    const float4 me = posq[i];

    // ---- top-16 nearest (excluding self), registers only (static indices) ----
    float bd[KK];
    int bi[KK];
#pragma unroll
    for (int t = 0; t < KK; ++t) { bd[t] = 1e30f; bi[t] = 0; }
    float worst = 1e30f;
    int wslot = 0;

    for (int j = 0; j < NN; ++j) {
        float4 p = posq[j];
        float dot = me.x * p.x + me.y * p.y + me.z * p.z;
        float d2 = me.w + p.w - 2.0f * dot;
        if (d2 < worst && j != i) {
#pragma unroll
            for (int t = 0; t < KK; ++t) {
                if (t == wslot) { bd[t] = d2; bi[t] = j; }
            }
            worst = bd[0]; wslot = 0;
#pragma unroll
            for (int t = 1; t < KK; ++t) {
                if (bd[t] > worst) { worst = bd[t]; wslot = t; }
            }
        }
    }

    // ---- EdgeConv: sum_j leaky(leaky([xi, xj-xi] @ W1 + b1) @ W2 + b2) ----
    float acc[16];
#pragma unroll
    for (int o = 0; o < 16; ++o) acc[o] = 0.0f;

#pragma unroll 1
    for (int t = 0; t < KK; ++t) {
        float4 pj = posq[bi[t]];
        float in0 = me.x, in1 = me.y, in2 = me.z;
        float in3 = pj.x - me.x, in4 = pj.y - me.y, in5 = pj.z - me.z;
        float m1[16];
#pragma unroll
        for (int o = 0; o < 16; ++o) {
            float v = bb1[o];
            v += in0 * w1[0 * 16 + o];
            v += in1 * w1[1 * 16 + o];
            v += in2 * w1[2 * 16 + o];
            v += in3 * w1[3 * 16 + o];
            v += in4 * w1[4 * 16 + o];
            v += in5 * w1[5 * 16 + o];
            m1[o] = leaky(v);
        }
#pragma unroll
        for (int o = 0; o < 16; ++o) {
            float v = bb2[o];
#pragma unroll
            for (int f = 0; f < 16; ++f) v += m1[f] * w2[f * 16 + o];
            acc[o] += leaky(v);
        }
    }

    float4* out = (float4*)(h1 + (size_t)(g * NN + i) * 16);
    out[0] = make_float4(acc[0], acc[1], acc[2], acc[3]);
    out[1] = make_float4(acc[4], acc[5], acc[6], acc[7]);
    out[2] = make_float4(acc[8], acc[9], acc[10], acc[11]);
    out[3] = make_float4(acc[12], acc[13], acc[14], acc[15]);
}

// ---------------- Layer 2: fused kNN (on h1[:,:3]) + EdgeConv [32->16->16] ----------
__global__ __launch_bounds__(256) void knn_conv2(
    const float* __restrict__ h1,   // [NG*NN*16]
    const float* __restrict__ W1,   // [32*16]
    const float* __restrict__ b1,   // [16]
    const float* __restrict__ W2,   // [16*16]
    const float* __restrict__ b2,   // [16]
    float* __restrict__ h2)         // [NG*NN*16]
{
    __shared__ float4 posq[NN];
    __shared__ float w1[32 * 16];
    __shared__ float w2[16 * 16];
    __shared__ float bb1[16], bb2[16];

    const int g = blockIdx.x >> 2;
    const int chunk = blockIdx.x & 3;
    const int tid = threadIdx.x;

    w1[tid] = W1[tid];
    w1[256 + tid] = W1[256 + tid];
    w2[tid] = W2[tid];
    if (tid < 16) { bb1[tid] = b1[tid]; bb2[tid] = b2[tid]; }

    for (int n = tid; n < NN; n += 256) {
        const float* hp = h1 + (size_t)(g * NN + n) * 16;
        float px = hp[0], py = hp[1], pz = hp[2];
        posq[n] = make_float4(px, py, pz, px * px + py * py + pz * pz);
    }
    __syncthreads();

    const int i = chunk * 256 + tid;
    const float4 me = posq[i];

    float bd[KK];
    int bi[KK];
#pragma unroll
    for (int t = 0; t < KK; ++t) { bd[t] = 1e30f; bi[t] = 0; }
    float worst = 1e30f;
    int wslot = 0;

    for (int j = 0; j < NN; ++j) {
        float4 p = posq[j];
        float dot = me.x * p.x + me.y * p.y + me.z * p.z;
        float d2 = me.w + p.w - 2.0f * dot;
        if (d2 < worst && j != i) {
#pragma unroll
            for (int t = 0; t < KK; ++t) {
                if (t == wslot) { bd[t] = d2; bi[t] = j; }
            }
            worst = bd[0]; wslot = 0;
#pragma unroll
            for (int t = 1; t < KK; ++t) {
                if (bd[t] > worst) { worst = bd[t]; wslot = t; }
            }
        }
    }

    // own features (16)
    const float4* mp4 = (const float4*)(h1 + (size_t)(g * NN + i) * 16);
    float4 a0 = mp4[0], a1 = mp4[1], a2 = mp4[2], a3 = mp4[3];
    float xi[16] = {a0.x, a0.y, a0.z, a0.w, a1.x, a1.y, a1.z, a1.w,
                    a2.x, a2.y, a2.z, a2.w, a3.x, a3.y, a3.z, a3.w};

    float acc[16];
#pragma unroll
    for (int o = 0; o < 16; ++o) acc[o] = 0.0f;

#pragma unroll 1
    for (int t = 0; t < KK; ++t) {
        const float4* jp4 = (const float4*)(h1 + (size_t)(g * NN + bi[t]) * 16);
        float4 j0 = jp4[0], j1 = jp4[1], j2 = jp4[2], j3 = jp4[3];
        float xj[16] = {j0.x, j0.y, j0.z, j0.w, j1.x, j1.y, j1.z, j1.w,
                        j2.x, j2.y, j2.z, j2.w, j3.x, j3.y, j3.z, j3.w};
        float m1[16];
#pragma unroll
        for (int o = 0; o < 16; ++o) {
            float v = bb1[o];
#pragma unroll
            for (int f = 0; f < 16; ++f) v += xi[f] * w1[f * 16 + o];
#pragma unroll
            for (int f = 0; f < 16; ++f) v += (xj[f] - xi[f]) * w1[(16 + f) * 16 + o];
            m1[o] = leaky(v);
        }
#pragma unroll
        for (int o = 0; o < 16; ++o) {
            float v = bb2[o];
#pragma unroll
            for (int f = 0; f < 16; ++f) v += m1[f] * w2[f * 16 + o];
            acc[o] += leaky(v);
        }
    }

    float4* out = (float4*)(h2 + (size_t)(g * NN + i) * 16);
    out[0] = make_float4(acc[0], acc[1], acc[2], acc[3]);
    out[1] = make_float4(acc[4], acc[5], acc[6], acc[7]);
    out[2] = make_float4(acc[8], acc[9], acc[10], acc[11]);
    out[3] = make_float4(acc[12], acc[13], acc[14], acc[15]);
}

// ---------------- Post MLP [35->16->16] + min/max/mean pool + readout [48->128->10] --
__global__ __launch_bounds__(256) void post_pool_readout(
    const float* __restrict__ x,    // [NG*NN*3]
    const float* __restrict__ h1,   // [NG*NN*16]
    const float* __restrict__ h2,   // [NG*NN*16]
    const float* __restrict__ Wp1, const float* __restrict__ bp1,   // [35*16],[16]
    const float* __restrict__ Wp2, const float* __restrict__ bp2,   // [16*16],[16]
    const float* __restrict__ Wr1, const float* __restrict__ br1,   // [48*128],[128]
    const float* __restrict__ Wr2, const float* __restrict__ br2,   // [128*10],[10]
    float* __restrict__ out)        // [NG*10]
{
    __shared__ float wp1[35 * 16];
    __shared__ float wp2[16 * 16];
    __shared__ float sbp1[16], sbp2[16];
    __shared__ float wr1[48 * 128];
    __shared__ float sbr1[128];
    __shared__ float wr2[128 * 10];
    __shared__ float sbr2[10];
    __shared__ float red[3][4][16];
    __shared__ float pooled[48];
    __shared__ float hidden[128];

    const int g = blockIdx.x;
    const int tid = threadIdx.x;

    for (int t = tid; t < 560; t += 256) wp1[t] = Wp1[t];
    wp2[tid] = Wp2[tid];
    for (int t = tid; t < 6144; t += 256) wr1[t] = Wr1[t];
    for (int t = tid; t < 1280; t += 256) wr2[t] = Wr2[t];
    if (tid < 128) sbr1[tid] = br1[tid];
    if (tid < 16) { sbp1[tid] = bp1[tid]; sbp2[tid] = bp2[tid]; }
    if (tid < 10) sbr2[tid] = br2[tid];
    __syncthreads();

    float mn[16], mx[16], sm[16];
#pragma unroll
    for (int o = 0; o < 16; ++o) { mn[o] = 1e30f; mx[o] = -1e30f; sm[o] = 0.0f; }

#pragma unroll 1
    for (int rep = 0; rep < 4; ++rep) {
        const int i = rep * 256 + tid;
        float feat[35];
        const float* xp = x + (size_t)(g * NN + i) * 3;
        feat[0] = xp[0]; feat[1] = xp[1]; feat[2] = xp[2];
        const float4* p1v = (const float4*)(h1 + (size_t)(g * NN + i) * 16);
        const float4* p2v = (const float4*)(h2 + (size_t)(g * NN + i) * 16);
#pragma unroll
        for (int q = 0; q < 4; ++q) {
            float4 v = p1v[q];
            feat[3 + 4 * q + 0] = v.x; feat[3 + 4 * q + 1] = v.y;
            feat[3 + 4 * q + 2] = v.z; feat[3 + 4 * q + 3] = v.w;
        }
#pragma unroll
        for (int q = 0; q < 4; ++q) {
            float4 v = p2v[q];
            feat[19 + 4 * q + 0] = v.x; feat[19 + 4 * q + 1] = v.y;
            feat[19 + 4 * q + 2] = v.z; feat[19 + 4 * q + 3] = v.w;
        }
        float p1[16];
#pragma unroll
        for (int o = 0; o < 16; ++o) {
            float v = sbp1[o];
#pragma unroll
            for (int f = 0; f < 35; ++f) v += feat[f] * wp1[f * 16 + o];
            p1[o] = leaky(v);
        }
#pragma unroll
        for (int o = 0; o < 16; ++o) {
            float v = sbp2[o];
#pragma unroll
            for (int f = 0; f < 16; ++f) v += p1[f] * wp2[f * 16 + o];
            float p2 = leaky(v);
            mn[o] = fminf(mn[o], p2);
            mx[o] = fmaxf(mx[o], p2);
            sm[o] += p2;
        }
    }

    // wave (64-lane) butterfly reduce
#pragma unroll
    for (int off = 32; off >= 1; off >>= 1) {
#pragma unroll
        for (int o = 0; o < 16; ++o) {
            mn[o] = fminf(mn[o], __shfl_xor(mn[o], off));
            mx[o] = fmaxf(mx[o], __shfl_xor(mx[o], off));
            sm[o] += __shfl_xor(sm[o], off);
        }
    }
    const int wave = tid >> 6;
    const int lane = tid & 63;
    if (lane == 0) {
#pragma unroll
        for (int o = 0; o < 16; ++o) {
            red[0][wave][o] = mn[o];
            red[1][wave][o] = mx[o];
            red[2][wave][o] = sm[o];
        }
    }
    __syncthreads();

    if (tid < 48) {
        const int stat = tid >> 4, o = tid & 15;
        float v;
        if (stat == 0)
            v = fminf(fminf(red[0][0][o], red[0][1][o]), fminf(red[0][2][o], red[0][3][o]));
        else if (stat == 1)
            v = fmaxf(fmaxf(red[1][0][o], red[1][1][o]), fmaxf(red[1][2][o], red[1][3][o]));
        else
            v = (red[2][0][o] + red[2][1][o] + red[2][2][o] + red[2][3][o]) * (1.0f / NN);
        pooled[tid] = v;
    }
    __syncthreads();

    if (tid < 128) {
        float v = sbr1[tid];
#pragma unroll
        for (int f = 0; f < 48; ++f) v += pooled[f] * wr1[f * 128 + tid];
        hidden[tid] = leaky(v);
    }
    __syncthreads();

    if (tid < 10) {
        float v = sbr2[tid];
#pragma unroll
        for (int f = 0; f < 128; ++f) v += hidden[f] * wr2[f * 10 + tid];
        out[g * 10 + tid] = v;
    }
}

extern "C" void kernel_launch(void* const* d_in, const int* in_sizes, int n_in,
                              void* d_out, int out_size, void* d_ws, size_t ws_size,
                              hipStream_t stream) {
    const float* x   = (const float*)d_in[0];
    // d_in[1] = batch (int32) — unused: graphs are equal-sized and sorted
    const float* W1a = (const float*)d_in[2];
    const float* b1a = (const float*)d_in[3];
    const float* W2a = (const float*)d_in[4];
    const float* b2a = (const float*)d_in[5];
    const float* W1b = (const float*)d_in[6];
    const float* b1b = (const float*)d_in[7];
    const float* W2b = (const float*)d_in[8];
    const float* b2b = (const float*)d_in[9];
    const float* Wp1 = (const float*)d_in[10];
    const float* bp1 = (const float*)d_in[11];
    const float* Wp2 = (const float*)d_in[12];
    const float* bp2 = (const float*)d_in[13];
    const float* Wr1 = (const float*)d_in[14];
    const float* br1 = (const float*)d_in[15];
    const float* Wr2 = (const float*)d_in[16];
    const float* br2 = (const float*)d_in[17];
    float* out = (float*)d_out;

    float* h1 = (float*)d_ws;                       // [NG*NN*16] = 8 MB
    float* h2 = h1 + (size_t)NG * NN * 16;          // [NG*NN*16] = 8 MB

    knn_conv1<<<NG * 4, 256, 0, stream>>>(x, W1a, b1a, W2a, b2a, h1);
    knn_conv2<<<NG * 4, 256, 0, stream>>>(h1, W1b, b1b, W2b, b2b, h2);
    post_pool_readout<<<NG, 256, 0, stream>>>(x, h1, h2, Wp1, bp1, Wp2, bp2,
                                              Wr1, br1, Wr2, br2, out);
}

// Round 2
// 1705.211 us; speedup vs baseline: 1.2907x; 1.2907x over previous
//
#include <hip/hip_runtime.h>

#define NG 128
#define NN 1024
#define KK 16
#define PCAP 8           // flush trigger
#define PMAX 12          // pending capacity (trigger checked per group of 4)
#define SLOPE 0.01f
#define FINF 3.0e38f

__device__ __forceinline__ float leaky(float v) {
    return v >= 0.0f ? v : SLOPE * v;
}

// branchless stable sorted insert (ascending by d; ties keep existing = earlier j)
__device__ __forceinline__ void sorted_insert(float (&bd)[KK], int (&bi)[KK],
                                              float d, int j) {
    bool c[KK];
#pragma unroll
    for (int t = 0; t < KK; ++t) c[t] = d < bd[t];
#pragma unroll
    for (int t = KK - 1; t >= 1; --t) {
        bd[t] = c[t] ? (c[t - 1] ? bd[t - 1] : d) : bd[t];
        bi[t] = c[t] ? (c[t - 1] ? bi[t - 1] : j) : bi[t];
    }
    bd[0] = c[0] ? d : bd[0];
    bi[0] = c[0] ? j : bi[0];
}

// exact top-16 nearest of node i among NN candidates (self excluded).
// posq: LDS float4 (x,y,z,|p|^2). pend_*: per-lane pending buffers (LDS).
__device__ __forceinline__ void knn_top16(const float4* posq,
                                          float* pend_d, unsigned short* pend_j,
                                          int tid, int i, float4 me,
                                          float (&bd)[KK], int (&bi)[KK]) {
#pragma unroll
    for (int t = 0; t < KK; ++t) { bd[t] = FINF; bi[t] = 0; }
    int cnt = 0;
    float T = FINF;

    for (int j0 = 0; j0 < NN; j0 += 4) {
        float4 p0 = posq[j0 + 0];
        float4 p1 = posq[j0 + 1];
        float4 p2 = posq[j0 + 2];
        float4 p3 = posq[j0 + 3];
#pragma unroll
        for (int u = 0; u < 4; ++u) {
            const int j = j0 + u;
            float4 p = (u == 0) ? p0 : (u == 1) ? p1 : (u == 2) ? p2 : p3;
            float dot = me.x * p.x + me.y * p.y + me.z * p.z;
            float d2 = me.w + p.w - 2.0f * dot;
            bool pass = (d2 < T) && (j != i);
            // branchless push: write always, commit via predicated increment
            pend_d[tid + 256 * cnt] = d2;
            pend_j[tid + 256 * cnt] = (unsigned short)j;
            cnt += pass ? 1 : 0;
        }
        if (__any(cnt >= PCAP)) {
#pragma unroll
            for (int s = 0; s < PCAP; ++s) {
                float d = pend_d[tid + 256 * s];
                int jj = pend_j[tid + 256 * s];
                sorted_insert(bd, bi, (s < cnt) ? d : FINF, jj);
            }
            if (__any(cnt > PCAP)) {
#pragma unroll
                for (int s = PCAP; s < PMAX; ++s) {
                    float d = pend_d[tid + 256 * s];
                    int jj = pend_j[tid + 256 * s];
                    sorted_insert(bd, bi, (s < cnt) ? d : FINF, jj);
                }
            }
            cnt = 0;
            T = bd[KK - 1];
        }
    }
    // final flush (cnt <= 7 here)
#pragma unroll
    for (int s = 0; s < PCAP; ++s) {
        float d = pend_d[tid + 256 * s];
        int jj = pend_j[tid + 256 * s];
        sorted_insert(bd, bi, (s < cnt) ? d : FINF, jj);
    }
}

// ---------------- Layer 1: fused kNN (on xyz) + EdgeConv [6->16->16], sum over k ----
__global__ __launch_bounds__(256, 2) void knn_conv1(
    const float* __restrict__ x,    // [NG*NN*3]
    const float* __restrict__ W1,   // [6*16]
    const float* __restrict__ b1,   // [16]
    const float* __restrict__ W2,   // [16*16]
    const float* __restrict__ b2,   // [16]
    float* __restrict__ h1)         // [NG*NN*16]
{
    __shared__ float4 posq[NN];
    __shared__ float pend_d[256 * PMAX];
    __shared__ unsigned short pend_j[256 * PMAX];
    __shared__ float w1[6 * 16];
    __shared__ float w2[16 * 16];
    __shared__ float bb1[16], bb2[16];

    const int g = blockIdx.x >> 2;
    const int chunk = blockIdx.x & 3;
    const int tid = threadIdx.x;

    if (tid < 96) w1[tid] = W1[tid];
    w2[tid] = W2[tid];
    if (tid < 16) { bb1[tid] = b1[tid]; bb2[tid] = b2[tid]; }

    for (int n = tid; n < NN; n += 256) {
        const float* xp = x + (size_t)(g * NN + n) * 3;
        float px = xp[0], py = xp[1], pz = xp[2];
        posq[n] = make_float4(px, py, pz, px * px + py * py + pz * pz);
    }
    __syncthreads();

    const int i = chunk * 256 + tid;
    const float4 me = posq[i];

    float bd[KK];
    int bi[KK];
    knn_top16(posq, pend_d, pend_j, tid, i, me, bd, bi);

    // ---- EdgeConv: sum_j leaky(leaky([xi, xj-xi] @ W1 + b1) @ W2 + b2) ----
    float acc[16];
#pragma unroll
    for (int o = 0; o < 16; ++o) acc[o] = 0.0f;

#pragma unroll 1
    for (int t = 0; t < KK; ++t) {
        float4 pj = posq[bi[t]];
        float in0 = me.x, in1 = me.y, in2 = me.z;
        float in3 = pj.x - me.x, in4 = pj.y - me.y, in5 = pj.z - me.z;
        float m1[16];
#pragma unroll
        for (int o = 0; o < 16; ++o) {
            float v = bb1[o];
            v += in0 * w1[0 * 16 + o];
            v += in1 * w1[1 * 16 + o];
            v += in2 * w1[2 * 16 + o];
            v += in3 * w1[3 * 16 + o];
            v += in4 * w1[4 * 16 + o];
            v += in5 * w1[5 * 16 + o];
            m1[o] = leaky(v);
        }
#pragma unroll
        for (int o = 0; o < 16; ++o) {
            float v = bb2[o];
#pragma unroll
            for (int f = 0; f < 16; ++f) v += m1[f] * w2[f * 16 + o];
            acc[o] += leaky(v);
        }
    }

    float4* out = (float4*)(h1 + (size_t)(g * NN + i) * 16);
    out[0] = make_float4(acc[0], acc[1], acc[2], acc[3]);
    out[1] = make_float4(acc[4], acc[5], acc[6], acc[7]);
    out[2] = make_float4(acc[8], acc[9], acc[10], acc[11]);
    out[3] = make_float4(acc[12], acc[13], acc[14], acc[15]);
}

// ---------------- Layer 2: fused kNN (on h1[:,:3]) + EdgeConv [32->16->16] ----------
__global__ __launch_bounds__(256, 2) void knn_conv2(
    const float* __restrict__ h1,   // [NG*NN*16]
    const float* __restrict__ W1,   // [32*16]
    const float* __restrict__ b1,   // [16]
    const float* __restrict__ W2,   // [16*16]
    const float* __restrict__ b2,   // [16]
    float* __restrict__ h2)         // [NG*NN*16]
{
    __shared__ float4 posq[NN];
    __shared__ float pend_d[256 * PMAX];
    __shared__ unsigned short pend_j[256 * PMAX];
    __shared__ float w1[32 * 16];
    __shared__ float w2[16 * 16];
    __shared__ float bb1[16], bb2[16];

    const int g = blockIdx.x >> 2;
    const int chunk = blockIdx.x & 3;
    const int tid = threadIdx.x;

    w1[tid] = W1[tid];
    w1[256 + tid] = W1[256 + tid];
    w2[tid] = W2[tid];
    if (tid < 16) { bb1[tid] = b1[tid]; bb2[tid] = b2[tid]; }

    for (int n = tid; n < NN; n += 256) {
        const float4 a = *(const float4*)(h1 + (size_t)(g * NN + n) * 16);
        posq[n] = make_float4(a.x, a.y, a.z, a.x * a.x + a.y * a.y + a.z * a.z);
    }
    __syncthreads();

    const int i = chunk * 256 + tid;
    const float4 me = posq[i];

    float bd[KK];
    int bi[KK];
    knn_top16(posq, pend_d, pend_j, tid, i, me, bd, bi);

    const float4* mp4 = (const float4*)(h1 + (size_t)(g * NN + i) * 16);
    float4 a0 = mp4[0], a1 = mp4[1], a2 = mp4[2], a3 = mp4[3];
    float xi[16] = {a0.x, a0.y, a0.z, a0.w, a1.x, a1.y, a1.z, a1.w,
                    a2.x, a2.y, a2.z, a2.w, a3.x, a3.y, a3.z, a3.w};

    float acc[16];
#pragma unroll
    for (int o = 0; o < 16; ++o) acc[o] = 0.0f;

#pragma unroll 1
    for (int t = 0; t < KK; ++t) {
        const float4* jp4 = (const float4*)(h1 + (size_t)(g * NN + bi[t]) * 16);
        float4 j0 = jp4[0], j1 = jp4[1], j2 = jp4[2], j3 = jp4[3];
        float xj[16] = {j0.x, j0.y, j0.z, j0.w, j1.x, j1.y, j1.z, j1.w,
                        j2.x, j2.y, j2.z, j2.w, j3.x, j3.y, j3.z, j3.w};
        float m1[16];
#pragma unroll
        for (int o = 0; o < 16; ++o) {
            float v = bb1[o];
#pragma unroll
            for (int f = 0; f < 16; ++f) v += xi[f] * w1[f * 16 + o];
#pragma unroll
            for (int f = 0; f < 16; ++f) v += (xj[f] - xi[f]) * w1[(16 + f) * 16 + o];
            m1[o] = leaky(v);
        }
#pragma unroll
        for (int o = 0; o < 16; ++o) {
            float v = bb2[o];
#pragma unroll
            for (int f = 0; f < 16; ++f) v += m1[f] * w2[f * 16 + o];
            acc[o] += leaky(v);
        }
    }

    float4* out = (float4*)(h2 + (size_t)(g * NN + i) * 16);
    out[0] = make_float4(acc[0], acc[1], acc[2], acc[3]);
    out[1] = make_float4(acc[4], acc[5], acc[6], acc[7]);
    out[2] = make_float4(acc[8], acc[9], acc[10], acc[11]);
    out[3] = make_float4(acc[12], acc[13], acc[14], acc[15]);
}

// ---------------- Post MLP [35->16->16] + min/max/mean pool + readout [48->128->10] --
__global__ __launch_bounds__(256) void post_pool_readout(
    const float* __restrict__ x,
    const float* __restrict__ h1,
    const float* __restrict__ h2,
    const float* __restrict__ Wp1, const float* __restrict__ bp1,
    const float* __restrict__ Wp2, const float* __restrict__ bp2,
    const float* __restrict__ Wr1, const float* __restrict__ br1,
    const float* __restrict__ Wr2, const float* __restrict__ br2,
    float* __restrict__ out)
{
    __shared__ float wp1[35 * 16];
    __shared__ float wp2[16 * 16];
    __shared__ float sbp1[16], sbp2[16];
    __shared__ float wr1[48 * 128];
    __shared__ float sbr1[128];
    __shared__ float wr2[128 * 10];
    __shared__ float sbr2[10];
    __shared__ float red[3][4][16];
    __shared__ float pooled[48];
    __shared__ float hidden[128];

    const int g = blockIdx.x;
    const int tid = threadIdx.x;

    for (int t = tid; t < 560; t += 256) wp1[t] = Wp1[t];
    wp2[tid] = Wp2[tid];
    for (int t = tid; t < 6144; t += 256) wr1[t] = Wr1[t];
    for (int t = tid; t < 1280; t += 256) wr2[t] = Wr2[t];
    if (tid < 128) sbr1[tid] = br1[tid];
    if (tid < 16) { sbp1[tid] = bp1[tid]; sbp2[tid] = bp2[tid]; }
    if (tid < 10) sbr2[tid] = br2[tid];
    __syncthreads();

    float mn[16], mx[16], sm[16];
#pragma unroll
    for (int o = 0; o < 16; ++o) { mn[o] = 1e30f; mx[o] = -1e30f; sm[o] = 0.0f; }

#pragma unroll 1
    for (int rep = 0; rep < 4; ++rep) {
        const int i = rep * 256 + tid;
        float feat[35];
        const float* xp = x + (size_t)(g * NN + i) * 3;
        feat[0] = xp[0]; feat[1] = xp[1]; feat[2] = xp[2];
        const float4* p1v = (const float4*)(h1 + (size_t)(g * NN + i) * 16);
        const float4* p2v = (const float4*)(h2 + (size_t)(g * NN + i) * 16);
#pragma unroll
        for (int q = 0; q < 4; ++q) {
            float4 v = p1v[q];
            feat[3 + 4 * q + 0] = v.x; feat[3 + 4 * q + 1] = v.y;
            feat[3 + 4 * q + 2] = v.z; feat[3 + 4 * q + 3] = v.w;
        }
#pragma unroll
        for (int q = 0; q < 4; ++q) {
            float4 v = p2v[q];
            feat[19 + 4 * q + 0] = v.x; feat[19 + 4 * q + 1] = v.y;
            feat[19 + 4 * q + 2] = v.z; feat[19 + 4 * q + 3] = v.w;
        }
        float p1[16];
#pragma unroll
        for (int o = 0; o < 16; ++o) {
            float v = sbp1[o];
#pragma unroll
            for (int f = 0; f < 35; ++f) v += feat[f] * wp1[f * 16 + o];
            p1[o] = leaky(v);
        }
#pragma unroll
        for (int o = 0; o < 16; ++o) {
            float v = sbp2[o];
#pragma unroll
            for (int f = 0; f < 16; ++f) v += p1[f] * wp2[f * 16 + o];
            float p2 = leaky(v);
            mn[o] = fminf(mn[o], p2);
            mx[o] = fmaxf(mx[o], p2);
            sm[o] += p2;
        }
    }

#pragma unroll
    for (int off = 32; off >= 1; off >>= 1) {
#pragma unroll
        for (int o = 0; o < 16; ++o) {
            mn[o] = fminf(mn[o], __shfl_xor(mn[o], off));
            mx[o] = fmaxf(mx[o], __shfl_xor(mx[o], off));
            sm[o] += __shfl_xor(sm[o], off);
        }
    }
    const int wave = tid >> 6;
    const int lane = tid & 63;
    if (lane == 0) {
#pragma unroll
        for (int o = 0; o < 16; ++o) {
            red[0][wave][o] = mn[o];
            red[1][wave][o] = mx[o];
            red[2][wave][o] = sm[o];
        }
    }
    __syncthreads();

    if (tid < 48) {
        const int stat = tid >> 4, o = tid & 15;
        float v;
        if (stat == 0)
            v = fminf(fminf(red[0][0][o], red[0][1][o]), fminf(red[0][2][o], red[0][3][o]));
        else if (stat == 1)
            v = fmaxf(fmaxf(red[1][0][o], red[1][1][o]), fmaxf(red[1][2][o], red[1][3][o]));
        else
            v = (red[2][0][o] + red[2][1][o] + red[2][2][o] + red[2][3][o]) * (1.0f / NN);
        pooled[tid] = v;
    }
    __syncthreads();

    if (tid < 128) {
        float v = sbr1[tid];
#pragma unroll
        for (int f = 0; f < 48; ++f) v += pooled[f] * wr1[f * 128 + tid];
        hidden[tid] = leaky(v);
    }
    __syncthreads();

    if (tid < 10) {
        float v = sbr2[tid];
#pragma unroll
        for (int f = 0; f < 128; ++f) v += hidden[f] * wr2[f * 10 + tid];
        out[g * 10 + tid] = v;
    }
}

extern "C" void kernel_launch(void* const* d_in, const int* in_sizes, int n_in,
                              void* d_out, int out_size, void* d_ws, size_t ws_size,
                              hipStream_t stream) {
    const float* x   = (const float*)d_in[0];
    const float* W1a = (const float*)d_in[2];
    const float* b1a = (const float*)d_in[3];
    const float* W2a = (const float*)d_in[4];
    const float* b2a = (const float*)d_in[5];
    const float* W1b = (const float*)d_in[6];
    const float* b1b = (const float*)d_in[7];
    const float* W2b = (const float*)d_in[8];
    const float* b2b = (const float*)d_in[9];
    const float* Wp1 = (const float*)d_in[10];
    const float* bp1 = (const float*)d_in[11];
    const float* Wp2 = (const float*)d_in[12];
    const float* bp2 = (const float*)d_in[13];
    const float* Wr1 = (const float*)d_in[14];
    const float* br1 = (const float*)d_in[15];
    const float* Wr2 = (const float*)d_in[16];
    const float* br2 = (const float*)d_in[17];
    float* out = (float*)d_out;

    float* h1 = (float*)d_ws;
    float* h2 = h1 + (size_t)NG * NN * 16;

    knn_conv1<<<NG * 4, 256, 0, stream>>>(x, W1a, b1a, W2a, b2a, h1);
    knn_conv2<<<NG * 4, 256, 0, stream>>>(h1, W1b, b1b, W2b, b2b, h2);
    post_pool_readout<<<NG, 256, 0, stream>>>(x, h1, h2, Wp1, bp1, Wp2, bp2,
                                              Wr1, br1, Wr2, br2, out);
}

// Round 3
// 1232.527 us; speedup vs baseline: 1.7858x; 1.3835x over previous
//
#include <hip/hip_runtime.h>

#define NG 128
#define NN 1024
#define KK 16
#define PCAP 8            // flush trigger (checked once per 8-candidate group)
#define PMAX 15           // max pending per lane (7 carry + 8 new)
#define SLOPE 0.01f
#define FINF 3.0e38f

__device__ __forceinline__ float leaky(float v) {
    return v >= 0.0f ? v : SLOPE * v;
}

// branchless stable sorted insert (ascending by d; ties keep existing = earlier j)
__device__ __forceinline__ void sorted_insert(float (&bd)[KK], int (&bi)[KK],
                                              float d, int j) {
    bool c[KK];
#pragma unroll
    for (int t = 0; t < KK; ++t) c[t] = d < bd[t];
#pragma unroll
    for (int t = KK - 1; t >= 1; --t) {
        bd[t] = c[t] ? (c[t - 1] ? bd[t - 1] : d) : bd[t];
        bi[t] = c[t] ? (c[t - 1] ? bi[t - 1] : j) : bi[t];
    }
    bd[0] = c[0] ? d : bd[0];
    bi[0] = c[0] ? j : bi[0];
}

// exact top-16 nearest of node i (self excluded); neighbor ids -> bi_lds[tid + 256*t].
// bd/bi live ONLY in registers (all static indexing). pend is per-lane LDS columns.
__device__ __forceinline__ void knn_top16(const float4* __restrict__ posq,
                                          unsigned long long* __restrict__ pend,
                                          unsigned int* __restrict__ bi_lds,
                                          int tid, int i, float4 me) {
    float bd[KK];
    int bi[KK];
#pragma unroll
    for (int t = 0; t < KK; ++t) { bd[t] = FINF; bi[t] = 0; }
    int cnt = 0;
    float T = FINF;

    for (int j0 = 0; j0 < NN; j0 += 8) {
        float4 p[8];
#pragma unroll
        for (int u = 0; u < 8; ++u) p[u] = posq[j0 + u];
#pragma unroll
        for (int u = 0; u < 8; ++u) {
            const int j = j0 + u;
            float dot = me.x * p[u].x + me.y * p[u].y + me.z * p[u].z;
            float d2 = me.w + p[u].w - 2.0f * dot;
            bool pass = (d2 < T) && (j != i);
            if (pass) {
                pend[tid + 256 * cnt] =
                    (((unsigned long long)__float_as_uint(d2)) << 32) | (unsigned int)j;
                ++cnt;
            }
        }
        if (__any(cnt >= PCAP)) {
#pragma unroll 1
            for (int s = 0; s < PMAX; ++s) {
                unsigned long long pk = pend[tid + 256 * s];
                float d = (s < cnt) ? __uint_as_float((unsigned int)(pk >> 32)) : FINF;
                int jj = (int)(unsigned int)(pk & 0xffffffffu);
                if (__any(d < bd[KK - 1])) sorted_insert(bd, bi, d, jj);
            }
            cnt = 0;
            T = bd[KK - 1];
        }
    }
#pragma unroll 1
    for (int s = 0; s < PCAP; ++s) {   // final: all lanes have cnt <= 7
        unsigned long long pk = pend[tid + 256 * s];
        float d = (s < cnt) ? __uint_as_float((unsigned int)(pk >> 32)) : FINF;
        int jj = (int)(unsigned int)(pk & 0xffffffffu);
        if (__any(d < bd[KK - 1])) sorted_insert(bd, bi, d, jj);
    }
#pragma unroll
    for (int t = 0; t < KK; ++t) bi_lds[tid + 256 * t] = (unsigned int)bi[t];
}

// ---------------- Layer 1: fused kNN (on xyz) + EdgeConv [6->16->16], sum over k ----
__global__ __launch_bounds__(256) void knn_conv1(
    const float* __restrict__ x,    // [NG*NN*3]
    const float* __restrict__ W1,   // [6*16]
    const float* __restrict__ b1,   // [16]
    const float* __restrict__ W2,   // [16*16]
    const float* __restrict__ b2,   // [16]
    float* __restrict__ h1)         // [NG*NN*16]
{
    __shared__ float4 posq[NN];                       // 16 KB
    __shared__ unsigned long long pend[256 * PMAX];   // 30 KB
    __shared__ unsigned int bi_lds[256 * KK];         // 16 KB
    __shared__ float w1[6 * 16];
    __shared__ float w2[16 * 16];
    __shared__ float bb1[16], bb2[16];

    const int g = blockIdx.x >> 2;
    const int chunk = blockIdx.x & 3;
    const int tid = threadIdx.x;

    if (tid < 96) w1[tid] = W1[tid];
    w2[tid] = W2[tid];
    if (tid < 16) { bb1[tid] = b1[tid]; bb2[tid] = b2[tid]; }

    for (int n = tid; n < NN; n += 256) {
        const float* xp = x + (size_t)(g * NN + n) * 3;
        float px = xp[0], py = xp[1], pz = xp[2];
        posq[n] = make_float4(px, py, pz, px * px + py * py + pz * pz);
    }
    __syncthreads();

    const int i = chunk * 256 + tid;
    const float4 me = posq[i];

    knn_top16(posq, pend, bi_lds, tid, i, me);

    float acc[16];
#pragma unroll
    for (int o = 0; o < 16; ++o) acc[o] = 0.0f;

#pragma unroll 1
    for (int t = 0; t < KK; ++t) {
        const int j = (int)bi_lds[tid + 256 * t];
        float4 pj = posq[j];
        float in3 = pj.x - me.x, in4 = pj.y - me.y, in5 = pj.z - me.z;
        float m1[16];
#pragma unroll
        for (int o = 0; o < 16; ++o) {
            float v = bb1[o];
            v += me.x * w1[0 * 16 + o];
            v += me.y * w1[1 * 16 + o];
            v += me.z * w1[2 * 16 + o];
            v += in3 * w1[3 * 16 + o];
            v += in4 * w1[4 * 16 + o];
            v += in5 * w1[5 * 16 + o];
            m1[o] = leaky(v);
        }
#pragma unroll
        for (int o = 0; o < 16; ++o) {
            float v = bb2[o];
#pragma unroll
            for (int f = 0; f < 16; ++f) v += m1[f] * w2[f * 16 + o];
            acc[o] += leaky(v);
        }
    }

    float4* out = (float4*)(h1 + (size_t)(g * NN + i) * 16);
    out[0] = make_float4(acc[0], acc[1], acc[2], acc[3]);
    out[1] = make_float4(acc[4], acc[5], acc[6], acc[7]);
    out[2] = make_float4(acc[8], acc[9], acc[10], acc[11]);
    out[3] = make_float4(acc[12], acc[13], acc[14], acc[15]);
}

// -------- Layer 2 + post-MLP + block-partial pooling, all fused -------------------
__global__ __launch_bounds__(256) void knn_conv2_post(
    const float* __restrict__ x,    // [NG*NN*3]
    const float* __restrict__ h1,   // [NG*NN*16]
    const float* __restrict__ W1,   // [32*16]
    const float* __restrict__ b1,   // [16]
    const float* __restrict__ W2,   // [16*16]
    const float* __restrict__ b2,   // [16]
    const float* __restrict__ Wp1, const float* __restrict__ bp1,   // [35*16],[16]
    const float* __restrict__ Wp2, const float* __restrict__ bp2,   // [16*16],[16]
    float* __restrict__ partial)    // [512*48]  (per-block: min16,max16,sum16)
{
    __shared__ float4 posq[NN];
    __shared__ unsigned long long pend[256 * PMAX];
    __shared__ unsigned int bi_lds[256 * KK];
    __shared__ float w1[32 * 16];
    __shared__ float w2[16 * 16];
    __shared__ float wp1[35 * 16];
    __shared__ float wp2[16 * 16];
    __shared__ float bb1[16], bb2[16], sbp1[16], sbp2[16];
    __shared__ float red[3][4][16];

    const int g = blockIdx.x >> 2;
    const int chunk = blockIdx.x & 3;
    const int tid = threadIdx.x;

    w1[tid] = W1[tid];
    w1[256 + tid] = W1[256 + tid];
    w2[tid] = W2[tid];
    wp2[tid] = Wp2[tid];
    for (int t = tid; t < 560; t += 256) wp1[t] = Wp1[t];
    if (tid < 16) {
        bb1[tid] = b1[tid]; bb2[tid] = b2[tid];
        sbp1[tid] = bp1[tid]; sbp2[tid] = bp2[tid];
    }

    for (int n = tid; n < NN; n += 256) {
        const float4 a = *(const float4*)(h1 + (size_t)(g * NN + n) * 16);
        posq[n] = make_float4(a.x, a.y, a.z, a.x * a.x + a.y * a.y + a.z * a.z);
    }
    __syncthreads();

    const int i = chunk * 256 + tid;
    const float4 me = posq[i];

    knn_top16(posq, pend, bi_lds, tid, i, me);

    // own features
    const float4* mp4 = (const float4*)(h1 + (size_t)(g * NN + i) * 16);
    float4 a0 = mp4[0], a1 = mp4[1], a2 = mp4[2], a3 = mp4[3];
    float xi[16] = {a0.x, a0.y, a0.z, a0.w, a1.x, a1.y, a1.z, a1.w,
                    a2.x, a2.y, a2.z, a2.w, a3.x, a3.y, a3.z, a3.w};

    float acc[16];
#pragma unroll
    for (int o = 0; o < 16; ++o) acc[o] = 0.0f;

#pragma unroll 1
    for (int t = 0; t < KK; ++t) {
        const int j = (int)bi_lds[tid + 256 * t];
        const float4* jp4 = (const float4*)(h1 + (size_t)(g * NN + j) * 16);
        float4 j0 = jp4[0], j1 = jp4[1], j2 = jp4[2], j3 = jp4[3];
        float xj[16] = {j0.x, j0.y, j0.z, j0.w, j1.x, j1.y, j1.z, j1.w,
                        j2.x, j2.y, j2.z, j2.w, j3.x, j3.y, j3.z, j3.w};
        float m1[16];
#pragma unroll
        for (int o = 0; o < 16; ++o) {
            float v = bb1[o];
#pragma unroll
            for (int f = 0; f < 16; ++f) v += xi[f] * w1[f * 16 + o];
#pragma unroll
            for (int f = 0; f < 16; ++f) v += (xj[f] - xi[f]) * w1[(16 + f) * 16 + o];
            m1[o] = leaky(v);
        }
#pragma unroll
        for (int o = 0; o < 16; ++o) {
            float v = bb2[o];
#pragma unroll
            for (int f = 0; f < 16; ++f) v += m1[f] * w2[f * 16 + o];
            acc[o] += leaky(v);
        }
    }

    // ---- post-MLP: feat = [x(3), h1(16), h2(16)] -> 16 -> 16 ----
    float feat[35];
    {
        const float* xp = x + (size_t)(g * NN + i) * 3;
        feat[0] = xp[0]; feat[1] = xp[1]; feat[2] = xp[2];
#pragma unroll
        for (int f = 0; f < 16; ++f) feat[3 + f] = xi[f];
#pragma unroll
        for (int f = 0; f < 16; ++f) feat[19 + f] = acc[f];
    }
    float p1[16];
#pragma unroll
    for (int o = 0; o < 16; ++o) {
        float v = sbp1[o];
#pragma unroll
        for (int f = 0; f < 35; ++f) v += feat[f] * wp1[f * 16 + o];
        p1[o] = leaky(v);
    }
    float mn[16], mx[16], sm[16];
#pragma unroll
    for (int o = 0; o < 16; ++o) {
        float v = sbp2[o];
#pragma unroll
        for (int f = 0; f < 16; ++f) v += p1[f] * wp2[f * 16 + o];
        float p2 = leaky(v);
        mn[o] = p2; mx[o] = p2; sm[o] = p2;
    }

    // wave butterfly reduce, then cross-wave combine
#pragma unroll
    for (int off = 32; off >= 1; off >>= 1) {
#pragma unroll
        for (int o = 0; o < 16; ++o) {
            mn[o] = fminf(mn[o], __shfl_xor(mn[o], off));
            mx[o] = fmaxf(mx[o], __shfl_xor(mx[o], off));
            sm[o] += __shfl_xor(sm[o], off);
        }
    }
    const int wave = tid >> 6;
    const int lane = tid & 63;
    if (lane == 0) {
#pragma unroll
        for (int o = 0; o < 16; ++o) {
            red[0][wave][o] = mn[o];
            red[1][wave][o] = mx[o];
            red[2][wave][o] = sm[o];
        }
    }
    __syncthreads();

    if (tid < 48) {
        const int stat = tid >> 4, o = tid & 15;
        float v;
        if (stat == 0)
            v = fminf(fminf(red[0][0][o], red[0][1][o]), fminf(red[0][2][o], red[0][3][o]));
        else if (stat == 1)
            v = fmaxf(fmaxf(red[1][0][o], red[1][1][o]), fmaxf(red[1][2][o], red[1][3][o]));
        else
            v = red[2][0][o] + red[2][1][o] + red[2][2][o] + red[2][3][o];
        partial[blockIdx.x * 48 + tid] = v;
    }
}

// -------- Finalize: combine 4 block-partials per graph + readout [48->128->10] -----
__global__ __launch_bounds__(128) void finalize(
    const float* __restrict__ partial,   // [512*48]
    const float* __restrict__ Wr1, const float* __restrict__ br1,   // [48*128],[128]
    const float* __restrict__ Wr2, const float* __restrict__ br2,   // [128*10],[10]
    float* __restrict__ out)             // [NG*10]
{
    __shared__ float pooled[48];
    __shared__ float hidden[128];

    const int g = blockIdx.x;
    const int tid = threadIdx.x;

    if (tid < 48) {
        const int stat = tid >> 4;
        float a = partial[(g * 4 + 0) * 48 + tid];
        float b = partial[(g * 4 + 1) * 48 + tid];
        float c = partial[(g * 4 + 2) * 48 + tid];
        float d = partial[(g * 4 + 3) * 48 + tid];
        float v;
        if (stat == 0)      v = fminf(fminf(a, b), fminf(c, d));
        else if (stat == 1) v = fmaxf(fmaxf(a, b), fmaxf(c, d));
        else                v = (a + b + c + d) * (1.0f / NN);
        pooled[tid] = v;
    }
    __syncthreads();

    {
        float v = br1[tid];
#pragma unroll
        for (int f = 0; f < 48; ++f) v += pooled[f] * Wr1[f * 128 + tid];
        hidden[tid] = leaky(v);
    }
    __syncthreads();

    if (tid < 10) {
        float v = br2[tid];
#pragma unroll
        for (int f = 0; f < 128; ++f) v += hidden[f] * Wr2[f * 10 + tid];
        out[g * 10 + tid] = v;
    }
}

extern "C" void kernel_launch(void* const* d_in, const int* in_sizes, int n_in,
                              void* d_out, int out_size, void* d_ws, size_t ws_size,
                              hipStream_t stream) {
    const float* x   = (const float*)d_in[0];
    const float* W1a = (const float*)d_in[2];
    const float* b1a = (const float*)d_in[3];
    const float* W2a = (const float*)d_in[4];
    const float* b2a = (const float*)d_in[5];
    const float* W1b = (const float*)d_in[6];
    const float* b1b = (const float*)d_in[7];
    const float* W2b = (const float*)d_in[8];
    const float* b2b = (const float*)d_in[9];
    const float* Wp1 = (const float*)d_in[10];
    const float* bp1 = (const float*)d_in[11];
    const float* Wp2 = (const float*)d_in[12];
    const float* bp2 = (const float*)d_in[13];
    const float* Wr1 = (const float*)d_in[14];
    const float* br1 = (const float*)d_in[15];
    const float* Wr2 = (const float*)d_in[16];
    const float* br2 = (const float*)d_in[17];
    float* out = (float*)d_out;

    float* h1 = (float*)d_ws;                              // 8 MB
    float* partial = h1 + (size_t)NG * NN * 16;            // 512*48 floats

    knn_conv1<<<NG * 4, 256, 0, stream>>>(x, W1a, b1a, W2a, b2a, h1);
    knn_conv2_post<<<NG * 4, 256, 0, stream>>>(x, h1, W1b, b1b, W2b, b2b,
                                               Wp1, bp1, Wp2, bp2, partial);
    finalize<<<NG, 128, 0, stream>>>(partial, Wr1, br1, Wr2, br2, out);
}